// Round 4
// baseline (1133.979 us; speedup 1.0000x reference)
//
#include <hip/hip_runtime.h>

#define HIDDEN 64
#define RSHIFT 6
#define RANGE 64  // 1 << RSHIFT nodes per bucket

// =====================  bucket CSR-build  =====================

__global__ __launch_bounds__(256) void bhist_kernel(const int* __restrict__ ei,
                                                    int* __restrict__ bcnt, int E) {
    int i = blockIdx.x * blockDim.x + threadIdx.x;
    int st = gridDim.x * blockDim.x;
    for (; i < E; i += st) atomicAdd(&bcnt[ei[E + i] >> RSHIFT], 1);
}

// Single-block multi-tile exclusive scan of bcnt[0..nb) -> boff, bcur; boff[nb]=E.
__global__ __launch_bounds__(256) void bscan_kernel(const int* __restrict__ bcnt,
                                                    int* __restrict__ boff,
                                                    int* __restrict__ bcur, int nb, int E) {
    __shared__ int s[256];
    __shared__ int carry;
    const int t = threadIdx.x;
    if (t == 0) carry = 0;
    __syncthreads();
    for (int base = 0; base < nb; base += 1024) {
        const int i0 = base + t * 4;
        int v0 = (i0 + 0 < nb) ? bcnt[i0 + 0] : 0;
        int v1 = (i0 + 1 < nb) ? bcnt[i0 + 1] : 0;
        int v2 = (i0 + 2 < nb) ? bcnt[i0 + 2] : 0;
        int v3 = (i0 + 3 < nb) ? bcnt[i0 + 3] : 0;
        const int mysum = v0 + v1 + v2 + v3;
        s[t] = mysum;
        __syncthreads();
        for (int d = 1; d < 256; d <<= 1) {
            int u = (t >= d) ? s[t - d] : 0;
            __syncthreads();
            s[t] += u;
            __syncthreads();
        }
        const int c = carry;
        const int excl = s[t] - mysum + c;
        if (i0 + 0 < nb) { boff[i0 + 0] = excl;                bcur[i0 + 0] = excl; }
        if (i0 + 1 < nb) { boff[i0 + 1] = excl + v0;           bcur[i0 + 1] = excl + v0; }
        if (i0 + 2 < nb) { boff[i0 + 2] = excl + v0 + v1;      bcur[i0 + 2] = excl + v0 + v1; }
        if (i0 + 3 < nb) { boff[i0 + 3] = excl + v0 + v1 + v2; bcur[i0 + 3] = excl + v0 + v1 + v2; }
        __syncthreads();
        if (t == 0) carry = c + s[255];
        __syncthreads();
    }
    if (t == 0) boff[nb] = E;
}

// Append {src | dstlocal<<20, eidx} into the dst's bucket segment (dense writes).
__global__ __launch_bounds__(256) void bscatter_kernel(const int* __restrict__ ei,
                                                       int* __restrict__ bcur,
                                                       int2* __restrict__ rec, int E) {
    int i = blockIdx.x * blockDim.x + threadIdx.x;
    int st = gridDim.x * blockDim.x;
    for (; i < E; i += st) {
        const int src = ei[i];
        const int dst = ei[E + i];
        const int b = dst >> RSHIFT;
        const int slot = atomicAdd(&bcur[b], 1);
        rec[slot] = make_int2(src | ((dst & (RANGE - 1)) << 20), i);
    }
}

// =====================  accumulate: one block per bucket, LDS node rows  =====================
__global__ __launch_bounds__(256) void accum_kernel(
    const float* __restrict__ x, const int* __restrict__ boff, const int2* __restrict__ rec,
    const float4* __restrict__ ea, const float* __restrict__ We, const float* __restrict__ be,
    float* __restrict__ hbuf, int N) {
    __shared__ float rows[RANGE * HIDDEN];  // 16 KB
    const int lane = threadIdx.x & 63;
    const int wid = threadIdx.x >> 6;  // 0..3
    const float w0 = We[lane];
    const float w1 = We[64 + lane];
    const float w2 = We[128 + lane];
    const float w3 = We[192 + lane];
    const float bb = be[lane];
    for (int i = threadIdx.x; i < RANGE * HIDDEN; i += blockDim.x) rows[i] = 0.0f;
    __syncthreads();

    const int b = blockIdx.x;
    const int s0 = boff[b];
    const int s1 = boff[b + 1];
    const int cnt = s1 - s0;
    const int per = (cnt + 3) >> 2;
    int s = s0 + wid * per;
    const int send = min(s + per, s1);

    for (; s + 4 <= send; s += 4) {
        const int2 r0 = rec[s + 0];
        const int2 r1 = rec[s + 1];
        const int2 r2 = rec[s + 2];
        const int2 r3 = rec[s + 3];
        const float4 a0 = ea[r0.y];
        const float4 a1 = ea[r1.y];
        const float4 a2 = ea[r2.y];
        const float4 a3 = ea[r3.y];
        const float x0 = x[(size_t)(r0.x & 0xFFFFF) * HIDDEN + lane];
        const float x1 = x[(size_t)(r1.x & 0xFFFFF) * HIDDEN + lane];
        const float x2 = x[(size_t)(r2.x & 0xFFFFF) * HIDDEN + lane];
        const float x3 = x[(size_t)(r3.x & 0xFFFFF) * HIDDEN + lane];
        const float m0 = fmaxf(x0 + (bb + a0.x * w0 + a0.y * w1 + a0.z * w2 + a0.w * w3), 0.0f);
        const float m1 = fmaxf(x1 + (bb + a1.x * w0 + a1.y * w1 + a1.z * w2 + a1.w * w3), 0.0f);
        const float m2 = fmaxf(x2 + (bb + a2.x * w0 + a2.y * w1 + a2.z * w2 + a2.w * w3), 0.0f);
        const float m3 = fmaxf(x3 + (bb + a3.x * w0 + a3.y * w1 + a3.z * w2 + a3.w * w3), 0.0f);
        atomicAdd(&rows[((r0.x >> 20) << 6) + lane], m0);
        atomicAdd(&rows[((r1.x >> 20) << 6) + lane], m1);
        atomicAdd(&rows[((r2.x >> 20) << 6) + lane], m2);
        atomicAdd(&rows[((r3.x >> 20) << 6) + lane], m3);
    }
    for (; s < send; ++s) {
        const int2 r = rec[s];
        const float4 a = ea[r.y];
        const float xv = x[(size_t)(r.x & 0xFFFFF) * HIDDEN + lane];
        const float m = fmaxf(xv + (bb + a.x * w0 + a.y * w1 + a.z * w2 + a.w * w3), 0.0f);
        atomicAdd(&rows[((r.x >> 20) << 6) + lane], m);
    }
    __syncthreads();

    const int base = b << RSHIFT;
    for (int r = wid; r < RANGE; r += 4) {
        const int node = base + r;
        if (node < N)
            hbuf[(size_t)node * HIDDEN + lane] =
                x[(size_t)node * HIDDEN + lane] + rows[(r << 6) + lane];
    }
}

// =====================  MLP via readlane broadcast (zero DS)  =====================
__device__ __forceinline__ float lane_bcast(float v, int l) {
    return __uint_as_float(__builtin_amdgcn_readlane(__float_as_uint(v), l));
}

__global__ __launch_bounds__(256) void mlp_kernel(const float* __restrict__ hin,
                                                  const float* __restrict__ W1,
                                                  const float* __restrict__ b1,
                                                  const float* __restrict__ W2,
                                                  const float* __restrict__ b2,
                                                  float* __restrict__ out, int N) {
    const int lane = threadIdx.x & 63;
    float w1c[64], w2c[64];
#pragma unroll
    for (int k = 0; k < 64; ++k) w1c[k] = W1[k * 64 + lane];
#pragma unroll
    for (int k = 0; k < 64; ++k) w2c[k] = W2[k * 64 + lane];
    const float bb1 = b1[lane];
    const float bb2 = b2[lane];
    int wave = (blockIdx.x * blockDim.x + threadIdx.x) >> 6;
    const int nw = (gridDim.x * blockDim.x) >> 6;
    for (int n = wave; n < N; n += nw) {
        const float h = hin[(size_t)n * HIDDEN + lane];
        float t0 = bb1, t1 = 0.0f;
#pragma unroll
        for (int k = 0; k < 64; k += 2) {
            t0 = fmaf(lane_bcast(h, k), w1c[k], t0);
            t1 = fmaf(lane_bcast(h, k + 1), w1c[k + 1], t1);
        }
        const float t = fmaxf(t0 + t1, 0.0f);
        float o0 = bb2, o1 = 0.0f;
#pragma unroll
        for (int k = 0; k < 64; k += 2) {
            o0 = fmaf(lane_bcast(t, k), w2c[k], o0);
            o1 = fmaf(lane_bcast(t, k + 1), w2c[k + 1], o1);
        }
        out[(size_t)n * HIDDEN + lane] = o0 + o1;
    }
}

// =====================  fallback (ws too small): atomic path  =====================
__global__ __launch_bounds__(256) void gine_copy_kernel(const float4* __restrict__ x,
                                                        float4* __restrict__ out, int n4) {
    int i = blockIdx.x * blockDim.x + threadIdx.x;
    int stride = gridDim.x * blockDim.x;
    for (; i < n4; i += stride) out[i] = x[i];
}

__global__ __launch_bounds__(256) void gine_edge_kernel(const float* __restrict__ x,
                                                        const int* __restrict__ ei,
                                                        const float4* __restrict__ ea,
                                                        const float* __restrict__ We,
                                                        const float* __restrict__ be,
                                                        float* __restrict__ out, int E) {
    const int lane = threadIdx.x & 63;
    const float w0 = We[lane];
    const float w1 = We[64 + lane];
    const float w2 = We[128 + lane];
    const float w3 = We[192 + lane];
    const float bb = be[lane];
    int wave = (blockIdx.x * blockDim.x + threadIdx.x) >> 6;
    const int nw = (gridDim.x * blockDim.x) >> 6;
    for (int e = wave; e < E; e += nw) {
        const int src = ei[e];
        const int dst = ei[E + e];
        const float4 a = ea[e];
        float m = x[src * HIDDEN + lane] + (bb + a.x * w0 + a.y * w1 + a.z * w2 + a.w * w3);
        m = fmaxf(m, 0.0f);
        atomicAdd(out + dst * HIDDEN + lane, m);
    }
}

extern "C" void kernel_launch(void* const* d_in, const int* in_sizes, int n_in,
                              void* d_out, int out_size, void* d_ws, size_t ws_size,
                              hipStream_t stream) {
    const float* x  = (const float*)d_in[0];
    const int*   ei = (const int*)d_in[1];
    const float* ea = (const float*)d_in[2];
    const float* We = (const float*)d_in[3];
    const float* be = (const float*)d_in[4];
    const float* W1 = (const float*)d_in[5];
    const float* b1 = (const float*)d_in[6];
    const float* W2 = (const float*)d_in[7];
    const float* b2 = (const float*)d_in[8];
    float* out = (float*)d_out;

    const int N = in_sizes[0] / HIDDEN;  // 100000
    const int E = in_sizes[1] / 2;       // 1600000
    const int nb = (N + RANGE - 1) >> RSHIFT;

    // Workspace layout
    size_t p = 0;
    const size_t bcnt_ofs = p; p += ((size_t)nb * 4 + 255) & ~(size_t)255;
    const size_t boff_ofs = p; p += ((size_t)(nb + 1) * 4 + 255) & ~(size_t)255;
    const size_t bcur_ofs = p; p += ((size_t)nb * 4 + 255) & ~(size_t)255;
    const size_t rec_ofs  = p; p += (size_t)E * 8;
    const size_t h_ofs    = p; p += (size_t)N * HIDDEN * 4;
    const size_t need = p;

    if (ws_size < need) {
        gine_copy_kernel<<<2048, 256, 0, stream>>>((const float4*)x, (float4*)out,
                                                   N * (HIDDEN / 4));
        gine_edge_kernel<<<2048, 256, 0, stream>>>(x, ei, (const float4*)ea, We, be, out, E);
        mlp_kernel<<<2048, 256, 0, stream>>>(out, W1, b1, W2, b2, out, N);
        return;
    }

    char* ws = (char*)d_ws;
    int*   bcnt = (int*)(ws + bcnt_ofs);
    int*   boff = (int*)(ws + boff_ofs);
    int*   bcur = (int*)(ws + bcur_ofs);
    int2*  rec  = (int2*)(ws + rec_ofs);
    float* hbuf = (float*)(ws + h_ofs);

    hipMemsetAsync(bcnt, 0, (size_t)nb * 4, stream);
    bhist_kernel<<<2048, 256, 0, stream>>>(ei, bcnt, E);
    bscan_kernel<<<1, 256, 0, stream>>>(bcnt, boff, bcur, nb, E);
    bscatter_kernel<<<2048, 256, 0, stream>>>(ei, bcur, rec, E);
    accum_kernel<<<nb, 256, 0, stream>>>(x, boff, rec, (const float4*)ea, We, be, hbuf, N);
    mlp_kernel<<<2048, 256, 0, stream>>>(hbuf, W1, b1, W2, b2, out, N);
}

// Round 5
// 775.978 us; speedup vs baseline: 1.4614x; 1.4614x over previous
//
#include <hip/hip_runtime.h>

#define HIDDEN 64
#define RSHIFT 4
#define RANGE 16   // nodes per bucket
#define CAP 512    // LDS-staged records per bucket (Poisson mean 256; overflow handled)

// =====================  bucket CSR-build  =====================

__global__ __launch_bounds__(256) void bhist_kernel(const int* __restrict__ ei,
                                                    int* __restrict__ bcnt, int E) {
    int i = blockIdx.x * blockDim.x + threadIdx.x;
    int st = gridDim.x * blockDim.x;
    for (; i < E; i += st) atomicAdd(&bcnt[ei[E + i] >> RSHIFT], 1);
}

// Single-block multi-tile exclusive scan of bcnt[0..nb) -> boff, bcur; boff[nb]=E.
__global__ __launch_bounds__(256) void bscan_kernel(const int* __restrict__ bcnt,
                                                    int* __restrict__ boff,
                                                    int* __restrict__ bcur, int nb, int E) {
    __shared__ int s[256];
    __shared__ int carry;
    const int t = threadIdx.x;
    if (t == 0) carry = 0;
    __syncthreads();
    for (int base = 0; base < nb; base += 1024) {
        const int i0 = base + t * 4;
        int v0 = (i0 + 0 < nb) ? bcnt[i0 + 0] : 0;
        int v1 = (i0 + 1 < nb) ? bcnt[i0 + 1] : 0;
        int v2 = (i0 + 2 < nb) ? bcnt[i0 + 2] : 0;
        int v3 = (i0 + 3 < nb) ? bcnt[i0 + 3] : 0;
        const int mysum = v0 + v1 + v2 + v3;
        s[t] = mysum;
        __syncthreads();
        for (int d = 1; d < 256; d <<= 1) {
            int u = (t >= d) ? s[t - d] : 0;
            __syncthreads();
            s[t] += u;
            __syncthreads();
        }
        const int c = carry;
        const int excl = s[t] - mysum + c;
        if (i0 + 0 < nb) { boff[i0 + 0] = excl;                bcur[i0 + 0] = excl; }
        if (i0 + 1 < nb) { boff[i0 + 1] = excl + v0;           bcur[i0 + 1] = excl + v0; }
        if (i0 + 2 < nb) { boff[i0 + 2] = excl + v0 + v1;      bcur[i0 + 2] = excl + v0 + v1; }
        if (i0 + 3 < nb) { boff[i0 + 3] = excl + v0 + v1 + v2; bcur[i0 + 3] = excl + v0 + v1 + v2; }
        __syncthreads();
        if (t == 0) carry = c + s[255];
        __syncthreads();
    }
    if (t == 0) boff[nb] = E;
}

// Dense append into bucket segments; edge_attr folded into the record.
__global__ __launch_bounds__(256) void bscatter_kernel(const int* __restrict__ ei,
                                                       const float4* __restrict__ ea,
                                                       int* __restrict__ bcur,
                                                       int* __restrict__ meta,
                                                       float4* __restrict__ eas, int E) {
    int i = blockIdx.x * blockDim.x + threadIdx.x;
    int st = gridDim.x * blockDim.x;
    for (; i < E; i += st) {
        const int src = ei[i];
        const int dst = ei[E + i];
        const int b = dst >> RSHIFT;
        const int slot = atomicAdd(&bcur[b], 1);
        meta[slot] = src | ((dst & (RANGE - 1)) << 20);
        eas[slot] = ea[i];
    }
}

// =====================  accumulate: one block per bucket  =====================
// Records staged in LDS (coalesced) so the hot loop has ONE VMEM hop (x gather).
__global__ __launch_bounds__(256) void accum_kernel(
    const float* __restrict__ x, const int* __restrict__ boff, const int* __restrict__ meta,
    const float4* __restrict__ eas, const float* __restrict__ We, const float* __restrict__ be,
    float* __restrict__ hout, int N) {
    __shared__ float rows[RANGE * HIDDEN];  // 4 KB
    __shared__ int smeta[CAP];              // 2 KB
    __shared__ float4 seas[CAP];            // 8 KB
    const int lane = threadIdx.x & 63;
    const int wid = threadIdx.x >> 6;  // 0..3
    const float w0 = We[lane];
    const float w1 = We[64 + lane];
    const float w2 = We[128 + lane];
    const float w3 = We[192 + lane];
    const float bb = be[lane];

    const int b = blockIdx.x;
    const int s0 = boff[b];
    const int s1 = boff[b + 1];
    const int cnt = s1 - s0;
    const int c = min(cnt, CAP);

    for (int i = threadIdx.x; i < RANGE * HIDDEN; i += blockDim.x) rows[i] = 0.0f;
    for (int i = threadIdx.x; i < c; i += blockDim.x) {
        smeta[i] = meta[s0 + i];
        seas[i] = eas[s0 + i];
    }
    __syncthreads();

    // main loop over LDS-staged records, 4-way ILP, one wave per contiguous chunk
    const int per = (c + 3) >> 2;
    const int a0 = min(wid * per, c);
    const int a1 = min(a0 + per, c);
    int j = a0;
    for (; j + 4 <= a1; j += 4) {
        const int m0 = smeta[j + 0];
        const int m1 = smeta[j + 1];
        const int m2 = smeta[j + 2];
        const int m3 = smeta[j + 3];
        const float4 e0 = seas[j + 0];
        const float4 e1 = seas[j + 1];
        const float4 e2 = seas[j + 2];
        const float4 e3 = seas[j + 3];
        const float x0 = x[(size_t)(m0 & 0xFFFFF) * HIDDEN + lane];
        const float x1 = x[(size_t)(m1 & 0xFFFFF) * HIDDEN + lane];
        const float x2 = x[(size_t)(m2 & 0xFFFFF) * HIDDEN + lane];
        const float x3 = x[(size_t)(m3 & 0xFFFFF) * HIDDEN + lane];
        const float v0 = fmaxf(x0 + (bb + e0.x * w0 + e0.y * w1 + e0.z * w2 + e0.w * w3), 0.0f);
        const float v1 = fmaxf(x1 + (bb + e1.x * w0 + e1.y * w1 + e1.z * w2 + e1.w * w3), 0.0f);
        const float v2 = fmaxf(x2 + (bb + e2.x * w0 + e2.y * w1 + e2.z * w2 + e2.w * w3), 0.0f);
        const float v3 = fmaxf(x3 + (bb + e3.x * w0 + e3.y * w1 + e3.z * w2 + e3.w * w3), 0.0f);
        atomicAdd(&rows[((m0 >> 20) << 6) + lane], v0);
        atomicAdd(&rows[((m1 >> 20) << 6) + lane], v1);
        atomicAdd(&rows[((m2 >> 20) << 6) + lane], v2);
        atomicAdd(&rows[((m3 >> 20) << 6) + lane], v3);
    }
    for (; j < a1; ++j) {
        const int m = smeta[j];
        const float4 e = seas[j];
        const float xv = x[(size_t)(m & 0xFFFFF) * HIDDEN + lane];
        const float v = fmaxf(xv + (bb + e.x * w0 + e.y * w1 + e.z * w2 + e.w * w3), 0.0f);
        atomicAdd(&rows[((m >> 20) << 6) + lane], v);
    }
    // overflow records (cnt > CAP): straight from global (vanishingly rare)
    for (int sg = s0 + CAP + wid; sg < s1; sg += 4) {
        const int m = meta[sg];
        const float4 e = eas[sg];
        const float xv = x[(size_t)(m & 0xFFFFF) * HIDDEN + lane];
        const float v = fmaxf(xv + (bb + e.x * w0 + e.y * w1 + e.z * w2 + e.w * w3), 0.0f);
        atomicAdd(&rows[((m >> 20) << 6) + lane], v);
    }
    __syncthreads();

    const int base = b << RSHIFT;
    for (int r = wid; r < RANGE; r += 4) {
        const int node = base + r;
        if (node < N)
            hout[(size_t)node * HIDDEN + lane] =
                x[(size_t)node * HIDDEN + lane] + rows[(r << 6) + lane];
    }
}

// =====================  MLP via readlane broadcast (zero DS, in-place safe)  =====================
__device__ __forceinline__ float lane_bcast(float v, int l) {
    return __uint_as_float(__builtin_amdgcn_readlane(__float_as_uint(v), l));
}

__global__ __launch_bounds__(256) void mlp_kernel(const float* __restrict__ hin,
                                                  const float* __restrict__ W1,
                                                  const float* __restrict__ b1,
                                                  const float* __restrict__ W2,
                                                  const float* __restrict__ b2,
                                                  float* __restrict__ out, int N) {
    const int lane = threadIdx.x & 63;
    float w1c[64], w2c[64];
#pragma unroll
    for (int k = 0; k < 64; ++k) w1c[k] = W1[k * 64 + lane];
#pragma unroll
    for (int k = 0; k < 64; ++k) w2c[k] = W2[k * 64 + lane];
    const float bb1 = b1[lane];
    const float bb2 = b2[lane];
    int wave = (blockIdx.x * blockDim.x + threadIdx.x) >> 6;
    const int nw = (gridDim.x * blockDim.x) >> 6;
    for (int n = wave; n < N; n += nw) {
        const float h = hin[(size_t)n * HIDDEN + lane];
        float t0 = bb1, t1 = 0.0f;
#pragma unroll
        for (int k = 0; k < 64; k += 2) {
            t0 = fmaf(lane_bcast(h, k), w1c[k], t0);
            t1 = fmaf(lane_bcast(h, k + 1), w1c[k + 1], t1);
        }
        const float t = fmaxf(t0 + t1, 0.0f);
        float o0 = bb2, o1 = 0.0f;
#pragma unroll
        for (int k = 0; k < 64; k += 2) {
            o0 = fmaf(lane_bcast(t, k), w2c[k], o0);
            o1 = fmaf(lane_bcast(t, k + 1), w2c[k + 1], o1);
        }
        out[(size_t)n * HIDDEN + lane] = o0 + o1;
    }
}

// =====================  fallback (ws too small): atomic path  =====================
__global__ __launch_bounds__(256) void gine_copy_kernel(const float4* __restrict__ x,
                                                        float4* __restrict__ out, int n4) {
    int i = blockIdx.x * blockDim.x + threadIdx.x;
    int stride = gridDim.x * blockDim.x;
    for (; i < n4; i += stride) out[i] = x[i];
}

__global__ __launch_bounds__(256) void gine_edge_kernel(const float* __restrict__ x,
                                                        const int* __restrict__ ei,
                                                        const float4* __restrict__ ea,
                                                        const float* __restrict__ We,
                                                        const float* __restrict__ be,
                                                        float* __restrict__ out, int E) {
    const int lane = threadIdx.x & 63;
    const float w0 = We[lane];
    const float w1 = We[64 + lane];
    const float w2 = We[128 + lane];
    const float w3 = We[192 + lane];
    const float bb = be[lane];
    int wave = (blockIdx.x * blockDim.x + threadIdx.x) >> 6;
    const int nw = (gridDim.x * blockDim.x) >> 6;
    for (int e = wave; e < E; e += nw) {
        const int src = ei[e];
        const int dst = ei[E + e];
        const float4 a = ea[e];
        float m = x[src * HIDDEN + lane] + (bb + a.x * w0 + a.y * w1 + a.z * w2 + a.w * w3);
        m = fmaxf(m, 0.0f);
        atomicAdd(out + dst * HIDDEN + lane, m);
    }
}

extern "C" void kernel_launch(void* const* d_in, const int* in_sizes, int n_in,
                              void* d_out, int out_size, void* d_ws, size_t ws_size,
                              hipStream_t stream) {
    const float* x  = (const float*)d_in[0];
    const int*   ei = (const int*)d_in[1];
    const float* ea = (const float*)d_in[2];
    const float* We = (const float*)d_in[3];
    const float* be = (const float*)d_in[4];
    const float* W1 = (const float*)d_in[5];
    const float* b1 = (const float*)d_in[6];
    const float* W2 = (const float*)d_in[7];
    const float* b2 = (const float*)d_in[8];
    float* out = (float*)d_out;

    const int N = in_sizes[0] / HIDDEN;  // 100000
    const int E = in_sizes[1] / 2;       // 1600000
    const int nb = (N + RANGE - 1) >> RSHIFT;

    // Workspace layout (h goes straight to d_out; mlp is in-place)
    size_t p = 0;
    const size_t bcnt_ofs = p; p += ((size_t)nb * 4 + 255) & ~(size_t)255;
    const size_t boff_ofs = p; p += ((size_t)(nb + 1) * 4 + 255) & ~(size_t)255;
    const size_t bcur_ofs = p; p += ((size_t)nb * 4 + 255) & ~(size_t)255;
    const size_t meta_ofs = p; p += ((size_t)E * 4 + 255) & ~(size_t)255;
    const size_t eas_ofs  = p; p += (size_t)E * 16;
    const size_t need = p;

    if (ws_size < need) {
        gine_copy_kernel<<<2048, 256, 0, stream>>>((const float4*)x, (float4*)out,
                                                   N * (HIDDEN / 4));
        gine_edge_kernel<<<2048, 256, 0, stream>>>(x, ei, (const float4*)ea, We, be, out, E);
        mlp_kernel<<<2048, 256, 0, stream>>>(out, W1, b1, W2, b2, out, N);
        return;
    }

    char* ws = (char*)d_ws;
    int*    bcnt = (int*)(ws + bcnt_ofs);
    int*    boff = (int*)(ws + boff_ofs);
    int*    bcur = (int*)(ws + bcur_ofs);
    int*    meta = (int*)(ws + meta_ofs);
    float4* eas  = (float4*)(ws + eas_ofs);

    hipMemsetAsync(bcnt, 0, (size_t)nb * 4, stream);
    bhist_kernel<<<2048, 256, 0, stream>>>(ei, bcnt, E);
    bscan_kernel<<<1, 256, 0, stream>>>(bcnt, boff, bcur, nb, E);
    bscatter_kernel<<<2048, 256, 0, stream>>>(ei, (const float4*)ea, bcur, meta, eas, E);
    accum_kernel<<<nb, 256, 0, stream>>>(x, boff, meta, eas, We, be, out, N);
    mlp_kernel<<<2048, 256, 0, stream>>>(out, W1, b1, W2, b2, out, N);
}

// Round 6
// 310.847 us; speedup vs baseline: 3.6480x; 2.4963x over previous
//
#include <hip/hip_runtime.h>

#define HIDDEN 64

__device__ __forceinline__ float lane_bcast(float v, int l) {
    return __uint_as_float(__builtin_amdgcn_readlane(__float_as_uint(v), l));
}

// =====================  CSR-build kernels (per-node exact)  =====================

__global__ __launch_bounds__(256) void hist_kernel(const int* __restrict__ ei, int* __restrict__ cnt,
                                                   int E) {
    int i = blockIdx.x * blockDim.x + threadIdx.x;
    int stride = gridDim.x * blockDim.x;
    for (; i < E; i += stride) atomicAdd(&cnt[ei[E + i]], 1);
}

__global__ __launch_bounds__(256) void scan1_kernel(int* __restrict__ cnt, int* __restrict__ partial,
                                                    int N) {
    __shared__ int s[256];
    const int t = threadIdx.x;
    const int base = blockIdx.x * 1024 + t * 4;
    int v0 = (base + 0 < N) ? cnt[base + 0] : 0;
    int v1 = (base + 1 < N) ? cnt[base + 1] : 0;
    int v2 = (base + 2 < N) ? cnt[base + 2] : 0;
    int v3 = (base + 3 < N) ? cnt[base + 3] : 0;
    const int mysum = v0 + v1 + v2 + v3;
    s[t] = mysum;
    __syncthreads();
    for (int d = 1; d < 256; d <<= 1) {
        int u = (t >= d) ? s[t - d] : 0;
        __syncthreads();
        s[t] += u;
        __syncthreads();
    }
    const int excl = s[t] - mysum;
    if (base + 0 < N) cnt[base + 0] = excl;
    if (base + 1 < N) cnt[base + 1] = excl + v0;
    if (base + 2 < N) cnt[base + 2] = excl + v0 + v1;
    if (base + 3 < N) cnt[base + 3] = excl + v0 + v1 + v2;
    if (t == 255) partial[blockIdx.x] = s[255];
}

__global__ __launch_bounds__(256) void scan2_kernel(int* __restrict__ partial, int nb) {
    __shared__ int s[256];
    const int t = threadIdx.x;
    const int mysum = (t < nb) ? partial[t] : 0;
    s[t] = mysum;
    __syncthreads();
    for (int d = 1; d < 256; d <<= 1) {
        int u = (t >= d) ? s[t - d] : 0;
        __syncthreads();
        s[t] += u;
        __syncthreads();
    }
    if (t < nb) partial[t] = s[t] - mysum;
}

__global__ __launch_bounds__(256) void scan3_kernel(int* __restrict__ off, int* __restrict__ cur,
                                                    const int* __restrict__ partial, int N, int E) {
    int i = blockIdx.x * blockDim.x + threadIdx.x;
    if (i < N) {
        const int o = off[i] + partial[i >> 10];
        off[i] = o;
        cur[i] = o;
    }
    if (i == 0) off[N] = E;
}

// XCD-partitioned scatter: blocks in group g = blockIdx&7 (~one XCD under
// round-robin dispatch) place only edges with dst in the group's contiguous
// node range. Each pairs[] line is then written by one XCD -> no multi-XCD
// write-back amplification. Mapping is a locality heuristic only; any block
// writing any slot is still correct.
__global__ __launch_bounds__(256) void scatter_xcd_kernel(const int* __restrict__ ei,
                                                          int* __restrict__ cur,
                                                          int2* __restrict__ pairs, int E, int N) {
    const int grp = blockIdx.x & 7;
    const int gblk = blockIdx.x >> 3;
    const int nblk = gridDim.x >> 3;
    const int lo = (int)((long long)grp * N / 8);
    const int hi = (int)((long long)(grp + 1) * N / 8);
    int i = gblk * blockDim.x + threadIdx.x;
    const int st = nblk * blockDim.x;
    for (; i < E; i += st) {
        const int dst = ei[E + i];
        if (dst >= lo && dst < hi) {
            const int src = ei[i];
            const int slot = atomicAdd(&cur[dst], 1);
            pairs[slot] = make_int2(src, i);
        }
    }
}

// =====================  gather (proven round-3 structure)  =====================
// One wave per node; 4-way ILP; registers accumulate; writes h to out.
__global__ __launch_bounds__(256) void gather_kernel(
    const float* __restrict__ x, const int* __restrict__ off, const int2* __restrict__ pairs,
    const float4* __restrict__ ea, const float* __restrict__ We, const float* __restrict__ be,
    float* __restrict__ hout, int N) {
    const int lane = threadIdx.x & 63;
    const float w0 = We[lane];
    const float w1 = We[64 + lane];
    const float w2 = We[128 + lane];
    const float w3 = We[192 + lane];
    const float bb = be[lane];
    int wave = (blockIdx.x * blockDim.x + threadIdx.x) >> 6;
    const int nw = (gridDim.x * blockDim.x) >> 6;
    for (int n = wave; n < N; n += nw) {
        const int s0 = off[n];
        const int s1 = off[n + 1];
        float acc = x[(size_t)n * HIDDEN + lane];
        int s = s0;
        for (; s + 4 <= s1; s += 4) {
            const int2 p0 = pairs[s + 0];
            const int2 p1 = pairs[s + 1];
            const int2 p2 = pairs[s + 2];
            const int2 p3 = pairs[s + 3];
            const float4 a0 = ea[p0.y];
            const float4 a1 = ea[p1.y];
            const float4 a2 = ea[p2.y];
            const float4 a3 = ea[p3.y];
            const float x0 = x[(size_t)p0.x * HIDDEN + lane];
            const float x1 = x[(size_t)p1.x * HIDDEN + lane];
            const float x2 = x[(size_t)p2.x * HIDDEN + lane];
            const float x3 = x[(size_t)p3.x * HIDDEN + lane];
            acc += fmaxf(x0 + (bb + a0.x * w0 + a0.y * w1 + a0.z * w2 + a0.w * w3), 0.0f);
            acc += fmaxf(x1 + (bb + a1.x * w0 + a1.y * w1 + a1.z * w2 + a1.w * w3), 0.0f);
            acc += fmaxf(x2 + (bb + a2.x * w0 + a2.y * w1 + a2.z * w2 + a2.w * w3), 0.0f);
            acc += fmaxf(x3 + (bb + a3.x * w0 + a3.y * w1 + a3.z * w2 + a3.w * w3), 0.0f);
        }
        for (; s < s1; ++s) {
            const int2 p = pairs[s];
            const float4 a = ea[p.y];
            const float xv = x[(size_t)p.x * HIDDEN + lane];
            acc += fmaxf(xv + (bb + a.x * w0 + a.y * w1 + a.z * w2 + a.w * w3), 0.0f);
        }
        hout[(size_t)n * HIDDEN + lane] = acc;
    }
}

// =====================  MLP via readlane broadcast (in-place safe)  =====================
__global__ __launch_bounds__(256) void mlp_kernel(const float* __restrict__ hin,
                                                  const float* __restrict__ W1,
                                                  const float* __restrict__ b1,
                                                  const float* __restrict__ W2,
                                                  const float* __restrict__ b2,
                                                  float* __restrict__ out, int N) {
    const int lane = threadIdx.x & 63;
    float w1c[64], w2c[64];
#pragma unroll
    for (int k = 0; k < 64; ++k) w1c[k] = W1[k * 64 + lane];
#pragma unroll
    for (int k = 0; k < 64; ++k) w2c[k] = W2[k * 64 + lane];
    const float bb1 = b1[lane];
    const float bb2 = b2[lane];
    int wave = (blockIdx.x * blockDim.x + threadIdx.x) >> 6;
    const int nw = (gridDim.x * blockDim.x) >> 6;
    for (int n = wave; n < N; n += nw) {
        const float h = hin[(size_t)n * HIDDEN + lane];
        float t0 = bb1, t1 = 0.0f;
#pragma unroll
        for (int k = 0; k < 64; k += 2) {
            t0 = fmaf(lane_bcast(h, k), w1c[k], t0);
            t1 = fmaf(lane_bcast(h, k + 1), w1c[k + 1], t1);
        }
        const float t = fmaxf(t0 + t1, 0.0f);
        float o0 = bb2, o1 = 0.0f;
#pragma unroll
        for (int k = 0; k < 64; k += 2) {
            o0 = fmaf(lane_bcast(t, k), w2c[k], o0);
            o1 = fmaf(lane_bcast(t, k + 1), w2c[k + 1], o1);
        }
        out[(size_t)n * HIDDEN + lane] = o0 + o1;
    }
}

// =====================  fallback (ws too small): atomic path  =====================
__global__ __launch_bounds__(256) void gine_copy_kernel(const float4* __restrict__ x,
                                                        float4* __restrict__ out, int n4) {
    int i = blockIdx.x * blockDim.x + threadIdx.x;
    int stride = gridDim.x * blockDim.x;
    for (; i < n4; i += stride) out[i] = x[i];
}

__global__ __launch_bounds__(256) void gine_edge_kernel(const float* __restrict__ x,
                                                        const int* __restrict__ ei,
                                                        const float4* __restrict__ ea,
                                                        const float* __restrict__ We,
                                                        const float* __restrict__ be,
                                                        float* __restrict__ out, int E) {
    const int lane = threadIdx.x & 63;
    const float w0 = We[lane];
    const float w1 = We[64 + lane];
    const float w2 = We[128 + lane];
    const float w3 = We[192 + lane];
    const float bb = be[lane];
    int wave = (blockIdx.x * blockDim.x + threadIdx.x) >> 6;
    const int nw = (gridDim.x * blockDim.x) >> 6;
    for (int e = wave; e < E; e += nw) {
        const int src = ei[e];
        const int dst = ei[E + e];
        const float4 a = ea[e];
        float m = x[src * HIDDEN + lane] + (bb + a.x * w0 + a.y * w1 + a.z * w2 + a.w * w3);
        m = fmaxf(m, 0.0f);
        atomicAdd(out + dst * HIDDEN + lane, m);
    }
}

extern "C" void kernel_launch(void* const* d_in, const int* in_sizes, int n_in,
                              void* d_out, int out_size, void* d_ws, size_t ws_size,
                              hipStream_t stream) {
    const float* x  = (const float*)d_in[0];
    const int*   ei = (const int*)d_in[1];
    const float* ea = (const float*)d_in[2];
    const float* We = (const float*)d_in[3];
    const float* be = (const float*)d_in[4];
    const float* W1 = (const float*)d_in[5];
    const float* b1 = (const float*)d_in[6];
    const float* W2 = (const float*)d_in[7];
    const float* b2 = (const float*)d_in[8];
    float* out = (float*)d_out;

    const int N = in_sizes[0] / HIDDEN;  // 100000
    const int E = in_sizes[1] / 2;       // 1600000

    // Workspace layout (h goes straight to d_out; mlp runs in place)
    const size_t off_bytes = (size_t)(N + 1) * 4;
    size_t p = 0;
    const size_t off_ofs  = p; p += (off_bytes + 255) & ~(size_t)255;
    const size_t cur_ofs  = p; p += ((size_t)N * 4 + 255) & ~(size_t)255;
    const size_t part_ofs = p; p += 512 * 4;
    const size_t pair_ofs = p; p += (size_t)E * 8;
    const size_t need = p;

    if (ws_size < need) {
        gine_copy_kernel<<<2048, 256, 0, stream>>>((const float4*)x, (float4*)out,
                                                   N * (HIDDEN / 4));
        gine_edge_kernel<<<2048, 256, 0, stream>>>(x, ei, (const float4*)ea, We, be, out, E);
        mlp_kernel<<<2048, 256, 0, stream>>>(out, W1, b1, W2, b2, out, N);
        return;
    }

    char* ws = (char*)d_ws;
    int*  off   = (int*)(ws + off_ofs);
    int*  cur   = (int*)(ws + cur_ofs);
    int*  part  = (int*)(ws + part_ofs);
    int2* pairs = (int2*)(ws + pair_ofs);

    const int nb_scan = (N + 1023) / 1024;  // <= 256 for N <= 262144

    hipMemsetAsync(off, 0, off_bytes, stream);
    hist_kernel<<<2048, 256, 0, stream>>>(ei, off, E);
    scan1_kernel<<<nb_scan, 256, 0, stream>>>(off, part, N);
    scan2_kernel<<<1, 256, 0, stream>>>(part, nb_scan);
    scan3_kernel<<<(N + 255) / 256, 256, 0, stream>>>(off, cur, part, N, E);
    scatter_xcd_kernel<<<2048, 256, 0, stream>>>(ei, cur, pairs, E, N);
    gather_kernel<<<2048, 256, 0, stream>>>(x, off, pairs, (const float4*)ea, We, be, out, N);
    mlp_kernel<<<2048, 256, 0, stream>>>(out, W1, b1, W2, b2, out, N);
}

// Round 7
// 280.570 us; speedup vs baseline: 4.0417x; 1.1079x over previous
//
#include <hip/hip_runtime.h>

#define HIDDEN 64

__device__ __forceinline__ float lane_bcast(float v, int l) {
    return __uint_as_float(__builtin_amdgcn_readlane(__float_as_uint(v), l));
}

// bf16 round-to-nearest-even pack/unpack
__device__ __forceinline__ unsigned int f2b(float f) {
    unsigned int u = __float_as_uint(f);
    return (u + 0x7FFFu + ((u >> 16) & 1u)) >> 16;
}
__device__ __forceinline__ float b2f(unsigned int v) {
    return __uint_as_float(v << 16);
}

// =====================  x -> bf16 convert  =====================
__global__ __launch_bounds__(256) void xcvt_kernel(const float4* __restrict__ x,
                                                   ushort4* __restrict__ x16, int n4) {
    int i = blockIdx.x * blockDim.x + threadIdx.x;
    const int st = gridDim.x * blockDim.x;
    for (; i < n4; i += st) {
        const float4 v = x[i];
        ushort4 o;
        o.x = (unsigned short)f2b(v.x);
        o.y = (unsigned short)f2b(v.y);
        o.z = (unsigned short)f2b(v.z);
        o.w = (unsigned short)f2b(v.w);
        x16[i] = o;
    }
}

// =====================  CSR-build kernels (per-node exact)  =====================

__global__ __launch_bounds__(256) void hist_kernel(const int* __restrict__ ei, int* __restrict__ cnt,
                                                   int E) {
    int i = blockIdx.x * blockDim.x + threadIdx.x;
    int stride = gridDim.x * blockDim.x;
    for (; i < E; i += stride) atomicAdd(&cnt[ei[E + i]], 1);
}

__global__ __launch_bounds__(256) void scan1_kernel(int* __restrict__ cnt, int* __restrict__ partial,
                                                    int N) {
    __shared__ int s[256];
    const int t = threadIdx.x;
    const int base = blockIdx.x * 1024 + t * 4;
    int v0 = (base + 0 < N) ? cnt[base + 0] : 0;
    int v1 = (base + 1 < N) ? cnt[base + 1] : 0;
    int v2 = (base + 2 < N) ? cnt[base + 2] : 0;
    int v3 = (base + 3 < N) ? cnt[base + 3] : 0;
    const int mysum = v0 + v1 + v2 + v3;
    s[t] = mysum;
    __syncthreads();
    for (int d = 1; d < 256; d <<= 1) {
        int u = (t >= d) ? s[t - d] : 0;
        __syncthreads();
        s[t] += u;
        __syncthreads();
    }
    const int excl = s[t] - mysum;
    if (base + 0 < N) cnt[base + 0] = excl;
    if (base + 1 < N) cnt[base + 1] = excl + v0;
    if (base + 2 < N) cnt[base + 2] = excl + v0 + v1;
    if (base + 3 < N) cnt[base + 3] = excl + v0 + v1 + v2;
    if (t == 255) partial[blockIdx.x] = s[255];
}

__global__ __launch_bounds__(256) void scan2_kernel(int* __restrict__ partial, int nb) {
    __shared__ int s[256];
    const int t = threadIdx.x;
    const int mysum = (t < nb) ? partial[t] : 0;
    s[t] = mysum;
    __syncthreads();
    for (int d = 1; d < 256; d <<= 1) {
        int u = (t >= d) ? s[t - d] : 0;
        __syncthreads();
        s[t] += u;
        __syncthreads();
    }
    if (t < nb) partial[t] = s[t] - mysum;
}

__global__ __launch_bounds__(256) void scan3_kernel(int* __restrict__ off, int* __restrict__ cur,
                                                    const int* __restrict__ partial, int N, int E) {
    int i = blockIdx.x * blockDim.x + threadIdx.x;
    if (i < N) {
        const int o = off[i] + partial[i >> 10];
        off[i] = o;
        cur[i] = o;
    }
    if (i == 0) off[N] = E;
}

// XCD-partitioned scatter with edge-attr folding: group g = blockIdx&7 places
// only edges whose dst is in its contiguous 1/8 node range -> each record line
// is written by one XCD (no write-back amplification). ea is packed to bf16x4
// into the record so the gather never touches ea randomly.
__global__ __launch_bounds__(256) void scatter_fold_kernel(const int* __restrict__ ei,
                                                           const float4* __restrict__ ea,
                                                           int* __restrict__ cur,
                                                           int* __restrict__ srcs,
                                                           uint2* __restrict__ eab, int E, int N) {
    const int grp = blockIdx.x & 7;
    const int gblk = blockIdx.x >> 3;
    const int nblk = gridDim.x >> 3;
    const int lo = (int)((long long)grp * N / 8);
    const int hi = (int)((long long)(grp + 1) * N / 8);
    int i = gblk * blockDim.x + threadIdx.x;
    const int st = nblk * blockDim.x;
    for (; i < E; i += st) {
        const int dst = ei[E + i];
        if (dst >= lo && dst < hi) {
            const int src = ei[i];
            const float4 a = ea[i];
            const int slot = atomicAdd(&cur[dst], 1);
            srcs[slot] = src;
            eab[slot] = make_uint2(f2b(a.x) | (f2b(a.y) << 16), f2b(a.z) | (f2b(a.w) << 16));
        }
    }
}

// =====================  gather (bf16 x, sequential records)  =====================
// One wave per node; 4-way ILP; per-record chain is ONE random load (x16).
__global__ __launch_bounds__(256) void gather16_kernel(
    const float* __restrict__ x, const unsigned short* __restrict__ x16,
    const int* __restrict__ off, const int* __restrict__ srcs, const uint2* __restrict__ eab,
    const float* __restrict__ We, const float* __restrict__ be, float* __restrict__ hout, int N) {
    const int lane = threadIdx.x & 63;
    const float w0 = We[lane];
    const float w1 = We[64 + lane];
    const float w2 = We[128 + lane];
    const float w3 = We[192 + lane];
    const float bb = be[lane];
    int wave = (blockIdx.x * blockDim.x + threadIdx.x) >> 6;
    const int nw = (gridDim.x * blockDim.x) >> 6;
    for (int n = wave; n < N; n += nw) {
        const int s0 = off[n];
        const int s1 = off[n + 1];
        float acc = x[(size_t)n * HIDDEN + lane];
        int s = s0;
        for (; s + 4 <= s1; s += 4) {
            const int r0 = srcs[s + 0];
            const int r1 = srcs[s + 1];
            const int r2 = srcs[s + 2];
            const int r3 = srcs[s + 3];
            const uint2 e0 = eab[s + 0];
            const uint2 e1 = eab[s + 1];
            const uint2 e2 = eab[s + 2];
            const uint2 e3 = eab[s + 3];
            const float x0 = b2f(x16[(size_t)r0 * HIDDEN + lane]);
            const float x1 = b2f(x16[(size_t)r1 * HIDDEN + lane]);
            const float x2 = b2f(x16[(size_t)r2 * HIDDEN + lane]);
            const float x3 = b2f(x16[(size_t)r3 * HIDDEN + lane]);
            acc += fmaxf(x0 + (bb + b2f(e0.x & 0xFFFFu) * w0 + b2f(e0.x >> 16) * w1 +
                               b2f(e0.y & 0xFFFFu) * w2 + b2f(e0.y >> 16) * w3), 0.0f);
            acc += fmaxf(x1 + (bb + b2f(e1.x & 0xFFFFu) * w0 + b2f(e1.x >> 16) * w1 +
                               b2f(e1.y & 0xFFFFu) * w2 + b2f(e1.y >> 16) * w3), 0.0f);
            acc += fmaxf(x2 + (bb + b2f(e2.x & 0xFFFFu) * w0 + b2f(e2.x >> 16) * w1 +
                               b2f(e2.y & 0xFFFFu) * w2 + b2f(e2.y >> 16) * w3), 0.0f);
            acc += fmaxf(x3 + (bb + b2f(e3.x & 0xFFFFu) * w0 + b2f(e3.x >> 16) * w1 +
                               b2f(e3.y & 0xFFFFu) * w2 + b2f(e3.y >> 16) * w3), 0.0f);
        }
        for (; s < s1; ++s) {
            const int r = srcs[s];
            const uint2 e = eab[s];
            const float xv = b2f(x16[(size_t)r * HIDDEN + lane]);
            acc += fmaxf(xv + (bb + b2f(e.x & 0xFFFFu) * w0 + b2f(e.x >> 16) * w1 +
                               b2f(e.y & 0xFFFFu) * w2 + b2f(e.y >> 16) * w3), 0.0f);
        }
        hout[(size_t)n * HIDDEN + lane] = acc;
    }
}

// =====================  MLP via readlane broadcast (in-place safe)  =====================
__global__ __launch_bounds__(256) void mlp_kernel(const float* __restrict__ hin,
                                                  const float* __restrict__ W1,
                                                  const float* __restrict__ b1,
                                                  const float* __restrict__ W2,
                                                  const float* __restrict__ b2,
                                                  float* __restrict__ out, int N) {
    const int lane = threadIdx.x & 63;
    float w1c[64], w2c[64];
#pragma unroll
    for (int k = 0; k < 64; ++k) w1c[k] = W1[k * 64 + lane];
#pragma unroll
    for (int k = 0; k < 64; ++k) w2c[k] = W2[k * 64 + lane];
    const float bb1 = b1[lane];
    const float bb2 = b2[lane];
    int wave = (blockIdx.x * blockDim.x + threadIdx.x) >> 6;
    const int nw = (gridDim.x * blockDim.x) >> 6;
    for (int n = wave; n < N; n += nw) {
        const float h = hin[(size_t)n * HIDDEN + lane];
        float t0 = bb1, t1 = 0.0f;
#pragma unroll
        for (int k = 0; k < 64; k += 2) {
            t0 = fmaf(lane_bcast(h, k), w1c[k], t0);
            t1 = fmaf(lane_bcast(h, k + 1), w1c[k + 1], t1);
        }
        const float t = fmaxf(t0 + t1, 0.0f);
        float o0 = bb2, o1 = 0.0f;
#pragma unroll
        for (int k = 0; k < 64; k += 2) {
            o0 = fmaf(lane_bcast(t, k), w2c[k], o0);
            o1 = fmaf(lane_bcast(t, k + 1), w2c[k + 1], o1);
        }
        out[(size_t)n * HIDDEN + lane] = o0 + o1;
    }
}

// =====================  fallback (ws too small): atomic path, fp32  =====================
__global__ __launch_bounds__(256) void gine_copy_kernel(const float4* __restrict__ x,
                                                        float4* __restrict__ out, int n4) {
    int i = blockIdx.x * blockDim.x + threadIdx.x;
    int stride = gridDim.x * blockDim.x;
    for (; i < n4; i += stride) out[i] = x[i];
}

__global__ __launch_bounds__(256) void gine_edge_kernel(const float* __restrict__ x,
                                                        const int* __restrict__ ei,
                                                        const float4* __restrict__ ea,
                                                        const float* __restrict__ We,
                                                        const float* __restrict__ be,
                                                        float* __restrict__ out, int E) {
    const int lane = threadIdx.x & 63;
    const float w0 = We[lane];
    const float w1 = We[64 + lane];
    const float w2 = We[128 + lane];
    const float w3 = We[192 + lane];
    const float bb = be[lane];
    int wave = (blockIdx.x * blockDim.x + threadIdx.x) >> 6;
    const int nw = (gridDim.x * blockDim.x) >> 6;
    for (int e = wave; e < E; e += nw) {
        const int src = ei[e];
        const int dst = ei[E + e];
        const float4 a = ea[e];
        float m = x[src * HIDDEN + lane] + (bb + a.x * w0 + a.y * w1 + a.z * w2 + a.w * w3);
        m = fmaxf(m, 0.0f);
        atomicAdd(out + dst * HIDDEN + lane, m);
    }
}

extern "C" void kernel_launch(void* const* d_in, const int* in_sizes, int n_in,
                              void* d_out, int out_size, void* d_ws, size_t ws_size,
                              hipStream_t stream) {
    const float* x  = (const float*)d_in[0];
    const int*   ei = (const int*)d_in[1];
    const float* ea = (const float*)d_in[2];
    const float* We = (const float*)d_in[3];
    const float* be = (const float*)d_in[4];
    const float* W1 = (const float*)d_in[5];
    const float* b1 = (const float*)d_in[6];
    const float* W2 = (const float*)d_in[7];
    const float* b2 = (const float*)d_in[8];
    float* out = (float*)d_out;

    const int N = in_sizes[0] / HIDDEN;  // 100000
    const int E = in_sizes[1] / 2;       // 1600000

    // Workspace layout (h goes straight to d_out; mlp runs in place)
    const size_t off_bytes = (size_t)(N + 1) * 4;
    size_t p = 0;
    const size_t off_ofs  = p; p += (off_bytes + 255) & ~(size_t)255;
    const size_t cur_ofs  = p; p += ((size_t)N * 4 + 255) & ~(size_t)255;
    const size_t part_ofs = p; p += 512 * 4;
    const size_t srcs_ofs = p; p += ((size_t)E * 4 + 255) & ~(size_t)255;
    const size_t eab_ofs  = p; p += ((size_t)E * 8 + 255) & ~(size_t)255;
    const size_t x16_ofs  = p; p += ((size_t)N * HIDDEN * 2 + 255) & ~(size_t)255;
    const size_t need = p;

    if (ws_size < need) {
        gine_copy_kernel<<<2048, 256, 0, stream>>>((const float4*)x, (float4*)out,
                                                   N * (HIDDEN / 4));
        gine_edge_kernel<<<2048, 256, 0, stream>>>(x, ei, (const float4*)ea, We, be, out, E);
        mlp_kernel<<<2048, 256, 0, stream>>>(out, W1, b1, W2, b2, out, N);
        return;
    }

    char* ws = (char*)d_ws;
    int*            off  = (int*)(ws + off_ofs);
    int*            cur  = (int*)(ws + cur_ofs);
    int*            part = (int*)(ws + part_ofs);
    int*            srcs = (int*)(ws + srcs_ofs);
    uint2*          eab  = (uint2*)(ws + eab_ofs);
    unsigned short* x16  = (unsigned short*)(ws + x16_ofs);

    const int nb_scan = (N + 1023) / 1024;  // <= 256 for N <= 262144

    xcvt_kernel<<<2048, 256, 0, stream>>>((const float4*)x, (ushort4*)x16, N * (HIDDEN / 4));
    hipMemsetAsync(off, 0, off_bytes, stream);
    hist_kernel<<<2048, 256, 0, stream>>>(ei, off, E);
    scan1_kernel<<<nb_scan, 256, 0, stream>>>(off, part, N);
    scan2_kernel<<<1, 256, 0, stream>>>(part, nb_scan);
    scan3_kernel<<<(N + 255) / 256, 256, 0, stream>>>(off, cur, part, N, E);
    scatter_fold_kernel<<<2048, 256, 0, stream>>>(ei, (const float4*)ea, cur, srcs, eab, E, N);
    gather16_kernel<<<2048, 256, 0, stream>>>(x, x16, off, srcs, eab, We, be, out, N);
    mlp_kernel<<<2048, 256, 0, stream>>>(out, W1, b1, W2, b2, out, N);
}